// Round 2
// baseline (49.990 us; speedup 1.0000x reference)
//
#include <hip/hip_runtime.h>
#include <hip/hip_bf16.h>

namespace {
constexpr int kH = 128, kW = 128, kN = 4096, kB = 2;
constexpr int kHW = kH * kW;                 // 16384
constexpr float kF = 500.0f, kC = 64.0f;     // FX=FY, CX=CY
constexpr float kLog2e = 1.4426950408889634f;
constexpr int kVLen = kB * kN * kW;          // 1,048,576 floats (4 MB)
constexpr int kALen = kB * kH * kN * 4;      // 4,194,304 floats (16 MB)
constexpr int kPixAll = kB * kHW;            // 32768 pixels
}

// Per-(batch, gaussian) camera transform -> projected center + exp2 coefficient.
__device__ __forceinline__ void gauss_cam(const float* __restrict__ pos,
                                          const float* __restrict__ scl,
                                          const float* __restrict__ qv,
                                          const float* __restrict__ tv,
                                          int b, int n,
                                          float& projx, float& projy, float& kcoef) {
  float qw = qv[4*b+0], qx = qv[4*b+1], qy = qv[4*b+2], qz = qv[4*b+3];
  float inv = rsqrtf(qw*qw + qx*qx + qy*qy + qz*qz);
  qw *= inv; qx *= inv; qy *= inv; qz *= inv;
  float R00 = 1.f - 2.f*(qy*qy + qz*qz);
  float R01 = 2.f*(qx*qy - qz*qw);
  float R02 = 2.f*(qx*qz + qy*qw);
  float R10 = 2.f*(qx*qy + qz*qw);
  float R11 = 1.f - 2.f*(qx*qx + qz*qz);
  float R12 = 2.f*(qy*qz - qx*qw);
  float R20 = 2.f*(qx*qz - qy*qw);
  float R21 = 2.f*(qy*qz + qx*qw);
  float R22 = 1.f - 2.f*(qx*qx + qy*qy);
  float px = pos[3*n+0], py = pos[3*n+1], pz = pos[3*n+2];
  float cxv = R00*px + R01*py + R02*pz + tv[3*b+0];
  float cyv = R10*px + R11*py + R12*pz + tv[3*b+1];
  float czv = R20*px + R21*py + R22*pz + tv[3*b+2];
  float iz = 1.0f / czv;
  projx = cxv * iz * kF + kC;
  projy = cyv * iz * kF + kC;
  float s = scl[n];
  kcoef = -0.5f * kLog2e / (s * s);   // exp(-0.5 d2/var) == exp2(kcoef * d2)
}

// Region 1 (first kVLen threads): V[b][n][x] = exp2(k*(x-px)^2)
// Region 2 (next kB*kH*kN threads): A[b][y][n] = u*{cr,cg,cb,1}, u = op*exp2(k*(y-py)^2)
__global__ __launch_bounds__(256) void prep_kernel(
    const float* __restrict__ pos, const float* __restrict__ col,
    const float* __restrict__ opa, const float* __restrict__ scl,
    const float* __restrict__ qv,  const float* __restrict__ tv,
    float* __restrict__ V, float4* __restrict__ A) {
  int t = blockIdx.x * 256 + threadIdx.x;
  if (t < kVLen) {
    int x = t & (kW - 1);
    int n = (t >> 7) & (kN - 1);
    int b = t >> 19;
    float projx, projy, kc;
    gauss_cam(pos, scl, qv, tv, b, n, projx, projy, kc);
    float d = (float)x - projx;
    V[t] = exp2f(kc * d * d);                       // t == (b*kN+n)*kW + x
  } else {
    int t2 = t - kVLen;
    int n = t2 & (kN - 1);
    int y = (t2 >> 12) & (kH - 1);
    int b = t2 >> 19;
    float projx, projy, kc;
    gauss_cam(pos, scl, qv, tv, b, n, projx, projy, kc);
    float d = (float)y - projy;
    float u = opa[n] * exp2f(kc * d * d);
    float cr = col[3*n+0], cg = col[3*n+1], cb = col[3*n+2];
    A[t2] = make_float4(u*cr, u*cg, u*cb, u);        // t2 == (b*kH+y)*kN + n
  }
}

// Each block: (chunk, b, 8 rows). Each wave: one row-pair (y, y+4), lane owns x=2l,2l+1.
// out4 partial[chunk][b][y][x] = sum_{n in chunk} A[b][y][n] * V[b][n][x]
__global__ __launch_bounds__(256) void accum_kernel(
    const float* __restrict__ V, const float4* __restrict__ A,
    float4* __restrict__ Part, int CS) {
  int blk = blockIdx.x;
  int chunk = blk >> 5;          // / (kB*16)
  int rem = blk & 31;
  int b = rem >> 4;
  int y0 = (rem & 15) << 3;      // 8 rows per block
  int wv = __builtin_amdgcn_readfirstlane((int)(threadIdx.x >> 6));
  int lane = (int)(threadIdx.x & 63);
  int ya = y0 + wv;
  int yb = ya + 4;
  int n0 = chunk * CS;
  const float* vp = V + (b * kN + n0) * kW + 2 * lane;
  const float4* a0p = A + (b * kH + ya) * kN + n0;
  const float4* a1p = A + (b * kH + yb) * kN + n0;
  float4 p00 = {0,0,0,0}, p01 = {0,0,0,0}, p10 = {0,0,0,0}, p11 = {0,0,0,0};
#pragma unroll 4
  for (int i = 0; i < CS; ++i) {
    float2 v = *(const float2*)vp; vp += kW;
    float4 a0 = a0p[i];
    float4 a1 = a1p[i];
    p00.x = fmaf(a0.x, v.x, p00.x); p00.y = fmaf(a0.y, v.x, p00.y);
    p00.z = fmaf(a0.z, v.x, p00.z); p00.w = fmaf(a0.w, v.x, p00.w);
    p01.x = fmaf(a0.x, v.y, p01.x); p01.y = fmaf(a0.y, v.y, p01.y);
    p01.z = fmaf(a0.z, v.y, p01.z); p01.w = fmaf(a0.w, v.y, p01.w);
    p10.x = fmaf(a1.x, v.x, p10.x); p10.y = fmaf(a1.y, v.x, p10.y);
    p10.z = fmaf(a1.z, v.x, p10.z); p10.w = fmaf(a1.w, v.x, p10.w);
    p11.x = fmaf(a1.x, v.y, p11.x); p11.y = fmaf(a1.y, v.y, p11.y);
    p11.z = fmaf(a1.z, v.y, p11.z); p11.w = fmaf(a1.w, v.y, p11.w);
  }
  int x0 = 2 * lane;
  long base = (long)(chunk * kB + b) * kHW;
  Part[base + ya * kW + x0]     = p00;
  Part[base + ya * kW + x0 + 1] = p01;
  Part[base + yb * kW + x0]     = p10;
  Part[base + yb * kW + x0 + 1] = p11;
}

__global__ __launch_bounds__(256) void finalize_kernel(
    const float4* __restrict__ Part, float* __restrict__ out, int NC) {
  int p = blockIdx.x * 256 + threadIdx.x;   // < kB*kHW
  int b = p >> 14;
  int yx = p & (kHW - 1);
  float4 s = {0,0,0,0};
  for (int c = 0; c < NC; ++c) {
    float4 t = Part[(size_t)(c * kB + b) * kHW + yx];
    s.x += t.x; s.y += t.y; s.z += t.z; s.w += t.w;
  }
  float den = fmaxf(s.w + 1e-8f, 1e-8f);
  float inv = 1.0f / den;
  out[(b * 3 + 0) * kHW + yx] = s.x * inv;
  out[(b * 3 + 1) * kHW + yx] = s.y * inv;
  out[(b * 3 + 2) * kHW + yx] = s.z * inv;
}

// ---------- fallback path (tiny workspace): direct per-pixel loop ----------
__global__ __launch_bounds__(256) void fb_params(
    const float* __restrict__ pos, const float* __restrict__ scl,
    const float* __restrict__ qv,  const float* __restrict__ tv,
    const float* __restrict__ opa, float4* __restrict__ Pa) {
  int t = blockIdx.x * 256 + threadIdx.x;   // < kB*kN
  int n = t & (kN - 1);
  int b = t >> 12;
  float px, py, kc;
  gauss_cam(pos, scl, qv, tv, b, n, px, py, kc);
  Pa[t] = make_float4(px, py, kc, opa[n]);
}

__global__ __launch_bounds__(256) void fb_render(
    const float4* __restrict__ Pa, const float* __restrict__ col,
    float* __restrict__ out) {
  int p = blockIdx.x * 256 + threadIdx.x;   // < kB*kHW
  int b = p >> 14;
  int yx = p & (kHW - 1);
  int y = yx >> 7, x = yx & (kW - 1);
  float ar = 0.f, ag = 0.f, ab = 0.f, ad = 0.f;
  for (int n = 0; n < kN; ++n) {
    float4 g = Pa[(b << 12) + n];
    float dx = (float)x - g.x;
    float dy = (float)y - g.y;
    float d2 = fmaf(dx, dx, dy * dy);
    float w = g.w * exp2f(g.z * d2);
    ar = fmaf(w, col[3*n+0], ar);
    ag = fmaf(w, col[3*n+1], ag);
    ab = fmaf(w, col[3*n+2], ab);
    ad += w;
  }
  float den = fmaxf(ad + 1e-8f, 1e-8f);
  float inv = 1.0f / den;
  out[(b * 3 + 0) * kHW + yx] = ar * inv;
  out[(b * 3 + 1) * kHW + yx] = ag * inv;
  out[(b * 3 + 2) * kHW + yx] = ab * inv;
}

extern "C" void kernel_launch(void* const* d_in, const int* in_sizes, int n_in,
                              void* d_out, int out_size, void* d_ws, size_t ws_size,
                              hipStream_t stream) {
  const float* pos = (const float*)d_in[0];
  const float* col = (const float*)d_in[1];
  const float* opa = (const float*)d_in[2];
  const float* scl = (const float*)d_in[3];
  const float* qv  = (const float*)d_in[4];
  const float* tv  = (const float*)d_in[5];
  float* out = (float*)d_out;
  float* ws = (float*)d_ws;

  const size_t part_floats_per_chunk = (size_t)kPixAll * 4;           // 131072
  const size_t need_min = ((size_t)kVLen + kALen + part_floats_per_chunk) * 4;

  if (ws_size >= need_min) {
    size_t avail = ws_size / 4 - (size_t)(kVLen + kALen);
    int nc = 16;
    while (nc > 1 && (size_t)nc * part_floats_per_chunk > avail) nc >>= 1;
    int cs = kN / nc;
    float* V = ws;
    float4* A = (float4*)(ws + kVLen);
    float4* Part = (float4*)(ws + kVLen + kALen);
    prep_kernel<<<dim3((kVLen + kB*kH*kN) / 256), dim3(256), 0, stream>>>(
        pos, col, opa, scl, qv, tv, V, A);
    accum_kernel<<<dim3(32 * nc), dim3(256), 0, stream>>>(V, A, Part, cs);
    finalize_kernel<<<dim3(kPixAll / 256), dim3(256), 0, stream>>>(Part, out, nc);
  } else {
    float4* Pa = (float4*)ws;   // 128 KB
    fb_params<<<dim3(kB * kN / 256), dim3(256), 0, stream>>>(pos, scl, qv, tv, opa, Pa);
    fb_render<<<dim3(kPixAll / 256), dim3(256), 0, stream>>>(Pa, col, out);
  }
}